// Round 1
// baseline (549.474 us; speedup 1.0000x reference)
//
#include <hip/hip_runtime.h>

#define CROP_H 14
#define CROP_W 14
#define NBOX   512
#define CH     256
#define IMH    200
#define IMW    200
#define PER_BOX (CH * CROP_H * CROP_W)   // 50176
#define BLOCKS_PER_BOX (PER_BOX / 256)   // 196

__global__ __launch_bounds__(256) void CropAndResize_60146722013533_kernel(
    const float* __restrict__ image,
    const float* __restrict__ boxes,
    const int*   __restrict__ box_idx,
    float*       __restrict__ out)
{
    const int n = blockIdx.y;          // box index
    const int t = threadIdx.x;

    __shared__ int   sy0[CROP_H], sy1[CROP_H], sx0[CROP_W], sx1[CROP_W];
    __shared__ float sly[CROP_H], slx[CROP_W];
    __shared__ int   svy[CROP_H], svx[CROP_W];
    __shared__ int   sb;

    if (t < CROP_H + CROP_W) {
        const float by1 = boxes[n * 4 + 0];
        const float bx1 = boxes[n * 4 + 1];
        const float by2 = boxes[n * 4 + 2];
        const float bx2 = boxes[n * 4 + 3];
        if (t < CROP_H) {
            const int gy = t;
            float h_scale = (by2 - by1) * (float)(IMH - 1) / (float)(CROP_H - 1);
            float in_y = by1 * (float)(IMH - 1) + (float)gy * h_scale;
            svy[gy] = (in_y >= 0.0f && in_y <= (float)(IMH - 1)) ? 1 : 0;
            float yf = floorf(in_y);
            sly[gy] = in_y - yf;
            sy0[gy] = (int)fminf(fmaxf(yf, 0.0f), (float)(IMH - 1));
            sy1[gy] = (int)fminf(fmaxf(ceilf(in_y), 0.0f), (float)(IMH - 1));
        } else {
            const int gx = t - CROP_H;
            float w_scale = (bx2 - bx1) * (float)(IMW - 1) / (float)(CROP_W - 1);
            float in_x = bx1 * (float)(IMW - 1) + (float)gx * w_scale;
            svx[gx] = (in_x >= 0.0f && in_x <= (float)(IMW - 1)) ? 1 : 0;
            float xf = floorf(in_x);
            slx[gx] = in_x - xf;
            sx0[gx] = (int)fminf(fmaxf(xf, 0.0f), (float)(IMW - 1));
            sx1[gx] = (int)fminf(fmaxf(ceilf(in_x), 0.0f), (float)(IMW - 1));
        }
    }
    if (t == 0) sb = box_idx[n];
    __syncthreads();

    // element within this box: [0, 50176)
    const int elem = blockIdx.x * 256 + t;
    const int c  = elem / (CROP_H * CROP_W);
    const int r  = elem - c * (CROP_H * CROP_W);
    const int gy = r / CROP_W;
    const int gx = r - gy * CROP_W;

    const float* base = image + ((size_t)(sb * CH + c)) * (size_t)(IMH * IMW);
    const int y0  = sy0[gy];
    const int y1i = sy1[gy];
    const int x0  = sx0[gx];
    const int x1i = sx1[gx];
    const float ly = sly[gy];
    const float lx = slx[gx];

    const float tl = base[y0  * IMW + x0 ];
    const float tr = base[y0  * IMW + x1i];
    const float bl = base[y1i * IMW + x0 ];
    const float br = base[y1i * IMW + x1i];

    const float top = tl + (tr - tl) * lx;
    const float bot = bl + (br - bl) * lx;
    float val = top + (bot - top) * ly;
    if (!(svy[gy] & svx[gx])) val = 0.0f;

    out[(size_t)n * PER_BOX + elem] = val;
}

extern "C" void kernel_launch(void* const* d_in, const int* in_sizes, int n_in,
                              void* d_out, int out_size, void* d_ws, size_t ws_size,
                              hipStream_t stream) {
    const float* image   = (const float*)d_in[0];
    const float* boxes   = (const float*)d_in[1];
    const int*   box_idx = (const int*)d_in[2];
    float* out = (float*)d_out;

    dim3 grid(BLOCKS_PER_BOX, NBOX, 1);
    dim3 block(256, 1, 1);
    CropAndResize_60146722013533_kernel<<<grid, block, 0, stream>>>(image, boxes, box_idx, out);
}

// Round 2
// 491.511 us; speedup vs baseline: 1.1179x; 1.1179x over previous
//
#include <hip/hip_runtime.h>

#define CROP_H 14
#define CROP_W 14
#define NBOX   512
#define CH     256
#define IMH    200
#define IMW    200
#define PER_BOX (CH * CROP_H * CROP_W)   // 50176
#define BLOCKS_PER_BOX (PER_BOX / 256)   // 196

// Grid is (x=box, y=chunk): blockIdx.x varies fastest in dispatch order, so at
// any instant the resident blocks cover a ~3-channel slice of ALL boxes/images
// (~4 MB working set -> L3/L2 resident; cross-box overlap served from cache).
__global__ __launch_bounds__(256) void CropAndResize_60146722013533_kernel(
    const float* __restrict__ image,
    const float* __restrict__ boxes,
    const int*   __restrict__ box_idx,
    float*       __restrict__ out)
{
    const int n = blockIdx.x;          // box index (fastest dispatch dim)
    const int t = threadIdx.x;

    __shared__ int   sy0[CROP_H], sy1[CROP_H], sx0[CROP_W], sx1[CROP_W];
    __shared__ float sly[CROP_H], slx[CROP_W];
    __shared__ int   svy[CROP_H], svx[CROP_W];
    __shared__ int   sb;

    if (t < CROP_H + CROP_W) {
        const float by1 = boxes[n * 4 + 0];
        const float bx1 = boxes[n * 4 + 1];
        const float by2 = boxes[n * 4 + 2];
        const float bx2 = boxes[n * 4 + 3];
        if (t < CROP_H) {
            const int gy = t;
            float h_scale = (by2 - by1) * (float)(IMH - 1) / (float)(CROP_H - 1);
            float in_y = by1 * (float)(IMH - 1) + (float)gy * h_scale;
            svy[gy] = (in_y >= 0.0f && in_y <= (float)(IMH - 1)) ? 1 : 0;
            float yf = floorf(in_y);
            sly[gy] = in_y - yf;
            sy0[gy] = (int)fminf(fmaxf(yf, 0.0f), (float)(IMH - 1));
            sy1[gy] = (int)fminf(fmaxf(ceilf(in_y), 0.0f), (float)(IMH - 1));
        } else {
            const int gx = t - CROP_H;
            float w_scale = (bx2 - bx1) * (float)(IMW - 1) / (float)(CROP_W - 1);
            float in_x = bx1 * (float)(IMW - 1) + (float)gx * w_scale;
            svx[gx] = (in_x >= 0.0f && in_x <= (float)(IMW - 1)) ? 1 : 0;
            float xf = floorf(in_x);
            slx[gx] = in_x - xf;
            sx0[gx] = (int)fminf(fmaxf(xf, 0.0f), (float)(IMW - 1));
            sx1[gx] = (int)fminf(fmaxf(ceilf(in_x), 0.0f), (float)(IMW - 1));
        }
    }
    if (t == 0) sb = box_idx[n];
    __syncthreads();

    // element within this box: [0, 50176)
    const int elem = blockIdx.y * 256 + t;
    const int c  = elem / (CROP_H * CROP_W);
    const int r  = elem - c * (CROP_H * CROP_W);
    const int gy = r / CROP_W;
    const int gx = r - gy * CROP_W;

    const float* base = image + ((size_t)(sb * CH + c)) * (size_t)(IMH * IMW);
    const int y0  = sy0[gy];
    const int y1i = sy1[gy];
    const int x0  = sx0[gx];
    const int x1i = sx1[gx];
    const float ly = sly[gy];
    const float lx = slx[gx];

    // tl/tr (and bl/br) are adjacent in x: x1i is always x0 or x0+1.
    // Load each pair as one 8B access anchored at xb = min(x0, W-2);
    // then both x0 and x1i are in {xb, xb+1}.
    const int xb = (x0 < IMW - 2) ? x0 : (IMW - 2);
    const float* rowt = base + y0  * IMW + xb;
    const float* rowb = base + y1i * IMW + xb;
    float2 vt, vb;
    __builtin_memcpy(&vt, rowt, 8);
    __builtin_memcpy(&vb, rowb, 8);

    const float tl = (x0  == xb) ? vt.x : vt.y;
    const float tr = (x1i == xb) ? vt.x : vt.y;
    const float bl = (x0  == xb) ? vb.x : vb.y;
    const float br = (x1i == xb) ? vb.x : vb.y;

    const float top = tl + (tr - tl) * lx;
    const float bot = bl + (br - bl) * lx;
    float val = top + (bot - top) * ly;
    if (!(svy[gy] & svx[gx])) val = 0.0f;

    out[(size_t)n * PER_BOX + elem] = val;
}

extern "C" void kernel_launch(void* const* d_in, const int* in_sizes, int n_in,
                              void* d_out, int out_size, void* d_ws, size_t ws_size,
                              hipStream_t stream) {
    const float* image   = (const float*)d_in[0];
    const float* boxes   = (const float*)d_in[1];
    const int*   box_idx = (const int*)d_in[2];
    float* out = (float*)d_out;

    dim3 grid(NBOX, BLOCKS_PER_BOX, 1);   // x = box (fastest), y = chunk
    dim3 block(256, 1, 1);
    CropAndResize_60146722013533_kernel<<<grid, block, 0, stream>>>(image, boxes, box_idx, out);
}